// Round 23
// baseline (117.449 us; speedup 1.0000x reference)
//
#include <hip/hip_runtime.h>
#include <hip/hip_bf16.h>

#define NE 1024       // N_EMBD
#define NH 16         // N_HEAD
#define HD 64         // HEAD_SIZE
#define TSEQ 2048
#define BATCH 2
#define MB (1024u * 1024u)

typedef __attribute__((ext_vector_type(8))) short bf16x8;
typedef __attribute__((ext_vector_type(4))) float f32x4;
typedef __attribute__((ext_vector_type(4))) unsigned int u32x4;
typedef unsigned short u16;
typedef unsigned int u32;

__device__ inline u16 f2bf(float f) {
    __hip_bfloat16 h = __float2bfloat16(f);
    return *reinterpret_cast<u16*>(&h);
}

__device__ inline float bf2f(u32 bits) {
    u32 v = bits << 16;
    return __builtin_bit_cast(float, v);
}

__device__ inline u32 cvt_pk_bf16(float lo, float hi) {
    u32 r;
    asm("v_cvt_pk_bf16_f32 %0, %1, %2" : "=v"(r) : "v"(lo), "v"(hi));
    return r;
}

#define GLD16(gptr, lptr)                                                        \
    __builtin_amdgcn_global_load_lds(                                            \
        (const __attribute__((address_space(1))) void*)(gptr),                   \
        (__attribute__((address_space(3))) void*)(lptr), 16, 0, 0)

// ---------- fused prep: x f32->bf16 convert + both weight transposes ----------
__global__ void k_prep(const float* __restrict__ x, u16* __restrict__ xb,
                       const float* __restrict__ Wa, const float* __restrict__ Wp,
                       u16* __restrict__ WaT, u16* __restrict__ WpT) {
    __shared__ float tile[32][33];
    const int bidx = blockIdx.x;
    if (bidx < 2048) {
        const int n4 = (BATCH * TSEQ * NE) / 4;
        int i = bidx * 256 + threadIdx.x;
        int stride = 2048 * 256;
        for (; i < n4; i += stride) {
            float4 v = reinterpret_cast<const float4*>(x)[i];
            ushort4 o;
            o.x = f2bf(v.x); o.y = f2bf(v.y); o.z = f2bf(v.z); o.w = f2bf(v.w);
            reinterpret_cast<ushort4*>(xb)[i] = o;
        }
        return;
    }
    int tb = bidx - 2048;
    const bool isA = tb < 3072;
    if (!isA) tb -= 3072;
    const float* in = isA ? Wa : Wp;
    u16* out = isA ? WaT : WpT;
    const int N = isA ? 3 * NE : NE;
    const int nbn = N / 32;
    int bn = (tb % nbn) * 32;
    int bk = (tb / nbn) * 32;
    int tx = threadIdx.x & 31, ty = threadIdx.x >> 5;
#pragma unroll
    for (int i = 0; i < 32; i += 8)
        tile[ty + i][tx] = in[(size_t)(bk + ty + i) * N + bn + tx];
    __syncthreads();
#pragma unroll
    for (int i = 0; i < 32; i += 8)
        out[(size_t)(bn + ty + i) * NE + bk + tx] = f2bf(tile[tx][ty + i]);
}

// ---------- GEMM: C[M,N] = A[M,K] * Bt[N,K]^T + bias ----------
// BK=32, double-buffered, BM templated, __launch_bounds__(256,3) (R20 best).
// MODE 0 (BM=128): q/k scatter [B,H,T,D]; v via LDS transpose -> [B,H,D,T].
// MODE 1: plain f32 out.
template <int MODE, int BM>
__global__ __launch_bounds__(256, 3) void k_gemm_bt(
    const u16* __restrict__ A, const u16* __restrict__ Bt,
    const float* __restrict__ bias, void* __restrict__ outp,
    int M, int N, int K) {
    constexpr int MI = BM / 32;
    constexpr int ACALLS = BM / 64;
    __shared__ __align__(16) u16 As[2][BM * 32];
    __shared__ __align__(16) u16 Bs[2][128 * 32];
    const int l = threadIdx.x & 63;
    const int w = threadIdx.x >> 6;
    const int m0 = blockIdx.x * BM;
    const int n0 = blockIdx.y * 128;
    const int wr = w >> 1, wc = w & 1;
    const int l15 = l & 15, g = l >> 4;
    const int srow = l >> 2;
    const int scol = (l & 3) * 8;

    f32x4 acc[MI][4] = {};
    const int nkt = K >> 5;

#pragma unroll
    for (int i = 0; i < ACALLS; ++i) {
        int c = w * ACALLS + i;
        GLD16(A + (size_t)(m0 + c * 16 + srow) * K + scol, &As[0][c * 512]);
    }
#pragma unroll
    for (int i = 0; i < 2; ++i) {
        int c = w * 2 + i;
        GLD16(Bt + (size_t)(n0 + c * 16 + srow) * K + scol, &Bs[0][c * 512]);
    }
    __syncthreads();

    int cur = 0;
    for (int kt = 0; kt < nkt; ++kt) {
        if (kt + 1 < nkt) {
            int nb = cur ^ 1;
            int kc = ((kt + 1) << 5) + scol;
#pragma unroll
            for (int i = 0; i < ACALLS; ++i) {
                int c = w * ACALLS + i;
                GLD16(A + (size_t)(m0 + c * 16 + srow) * K + kc, &As[nb][c * 512]);
            }
#pragma unroll
            for (int i = 0; i < 2; ++i) {
                int c = w * 2 + i;
                GLD16(Bt + (size_t)(n0 + c * 16 + srow) * K + kc, &Bs[nb][c * 512]);
            }
        }
        bf16x8 af[MI], bfr[4];
#pragma unroll
        for (int mi = 0; mi < MI; ++mi)
            af[mi] = *reinterpret_cast<const bf16x8*>(
                &As[cur][(wr * (BM / 2) + mi * 16 + l15) * 32 + g * 8]);
#pragma unroll
        for (int ni = 0; ni < 4; ++ni)
            bfr[ni] = *reinterpret_cast<const bf16x8*>(
                &Bs[cur][(wc * 64 + ni * 16 + l15) * 32 + g * 8]);
#pragma unroll
        for (int mi = 0; mi < MI; ++mi)
#pragma unroll
            for (int ni = 0; ni < 4; ++ni)
                acc[mi][ni] = __builtin_amdgcn_mfma_f32_16x16x32_bf16(af[mi], bfr[ni], acc[mi][ni], 0, 0, 0);
        __syncthreads();
        cur ^= 1;
    }

    if (MODE == 1) {
        float* C = (float*)outp;
#pragma unroll
        for (int mi = 0; mi < MI; ++mi)
#pragma unroll
            for (int ni = 0; ni < 4; ++ni) {
                int n = n0 + wc * 64 + ni * 16 + l15;
                float bv = bias[n];
#pragma unroll
                for (int r = 0; r < 4; ++r) {
                    int m = m0 + wr * (BM / 2) + mi * 16 + g * 4 + r;
                    C[(size_t)m * N + n] = acc[mi][ni][r] + bv;
                }
            }
    } else {
        u16* qkv = (u16*)outp;
        const size_t headsz = (size_t)BATCH * NH * TSEQ * HD;
        const int whichB = n0 >> 10;
        if (whichB < 2) {
#pragma unroll
            for (int mi = 0; mi < MI; ++mi)
#pragma unroll
                for (int ni = 0; ni < 4; ++ni) {
                    int n = n0 + wc * 64 + ni * 16 + l15;
                    float bv = bias[n];
                    int c = n & 1023;
                    int h = c >> 6, d = c & 63;
#pragma unroll
                    for (int r = 0; r < 4; ++r) {
                        int m = m0 + wr * (BM / 2) + mi * 16 + g * 4 + r;
                        int b = m >> 11, t = m & 2047;
                        float v = acc[mi][ni][r] + bv;
                        size_t dst = (size_t)whichB * headsz +
                                     ((size_t)(b * NH + h) * TSEQ + t) * HD + d;
                        qkv[dst] = f2bf(v);
                    }
                }
        } else {
            // v: transpose 128x128 subtile through dead staging LDS -> coalesced [B,H,D,T]
            u16* Vt = &As[0][0];
            __syncthreads();
#pragma unroll
            for (int mi = 0; mi < MI; ++mi)
#pragma unroll
                for (int ni = 0; ni < 4; ++ni) {
                    int nl = wc * 64 + ni * 16 + l15;
                    int ml = wr * (BM / 2) + mi * 16 + g * 4;
                    float bv = bias[n0 + nl];
                    u32* p = reinterpret_cast<u32*>(&Vt[nl * 128 + ml]);
                    p[0] = cvt_pk_bf16(acc[mi][ni][0] + bv, acc[mi][ni][1] + bv);
                    p[1] = cvt_pk_bf16(acc[mi][ni][2] + bv, acc[mi][ni][3] + bv);
                }
            __syncthreads();
            int nl = threadIdx.x >> 1;
            int mh = (threadIdx.x & 1) * 64;
            int b = m0 >> 11, t0l = m0 & 2047;
            int h = ((n0 & 1023) >> 6) + (nl >> 6);
            int d = nl & 63;
            u16* dst = qkv + 2 * headsz + ((size_t)(b * NH + h) * HD + d) * TSEQ + t0l + mh;
#pragma unroll
            for (int j = 0; j < 8; ++j)
                *reinterpret_cast<u32x4*>(dst + j * 8) =
                    *reinterpret_cast<const u32x4*>(&Vt[nl * 128 + mh + j * 8]);
        }
    }
}

// ---------- causal flash attention: QBLK=128 (2 q-frags/wave), NS-way K-split ----------
// grid: 16 * NS * 32 blocks, 4 waves, 32KB LDS, heavy-first. NS=4 measured optimum.
// launch_bounds (256,4): (256,5) spilled (R14); single-buffer V regressed (R17).
// setprio REMOVED this round: waves are barrier-locked per K-tile (m190 lockstep
// regime where setprio measured negative), never ablated here before.
template <int NS>
__global__ __launch_bounds__(256, 4) void k_attn(
    const u16* __restrict__ qb, const u16* __restrict__ kb, const u16* __restrict__ vtb,
    u16* __restrict__ oPart, float* __restrict__ mlPart) {
    __shared__ __align__(16) u16 Ks[2][64 * 64];
    __shared__ __align__(16) u16 Vs[2][64 * 64];
    const int l = threadIdx.x & 63;
    const int w = threadIdx.x >> 6;
    const int g = l >> 4, l15 = l & 15;

    const int bid = blockIdx.x;
    const int t = 15 - (bid / (NS * 32));   // 128-row q-tile, heavy first
    const int split = (bid / 32) % NS;
    const int bh = bid & 31;
    const int q0 = t * 128;
    const int ntk = 2 * t + 2;
    const int ktLo = (split * ntk) / NS;
    const int ktHi = ((split + 1) * ntk) / NS;

    const size_t base = (size_t)bh * TSEQ * HD;
    const u16* Q = qb + base;
    const u16* Kg = kb + base;
    const u16* Vg = vtb + base;  // [64 d][2048 t]

    const int lrow8 = l >> 3;
    const int lchunk = (l & 7) ^ lrow8;  // inverse-swizzled source chunk

    const int qrow0 = q0 + w * 32 + l15;
    const int qrow1 = qrow0 + 16;
    bf16x8 qa[2][2];  // [qn][ks]
#pragma unroll
    for (int ks = 0; ks < 2; ++ks) {
        qa[0][ks] = *reinterpret_cast<const bf16x8*>(Q + (size_t)qrow0 * HD + ks * 32 + g * 8);
        qa[1][ks] = *reinterpret_cast<const bf16x8*>(Q + (size_t)qrow1 * HD + ks * 32 + g * 8);
    }

    float m[2] = {0.f, 0.f};       // SAFE init (fully-masked rows stay finite)
    f32x4 o[2][4] = {};            // [qn][nf]
    f32x4 os[2] = {};              // ones-MFMA row-sum accumulators

    const float SC = 0.125f * 1.44269504f;  // log2(e)/sqrt(64)
    const float THRU = 44.3614f;            // 8/SC

    const int srcA = ((2 * g) & 3) * 16 + l15;
    const int srcB = ((2 * g + 1) & 3) * 16 + l15;
    const bool losel = (g < 2);

    u32x4 onesw = {0x3F803F80u, 0x3F803F80u, 0x3F803F80u, 0x3F803F80u};
    const bf16x8 onesA = __builtin_bit_cast(bf16x8, onesw);

    if (ktLo < ktHi) {
#pragma unroll
        for (int i2 = 0; i2 < 2; ++i2) {
            int c = w * 2 + i2;
            GLD16(Kg + (size_t)(ktLo * 64 + c * 8 + lrow8) * HD + lchunk * 8, &Ks[0][c * 512]);
            GLD16(Vg + (size_t)(c * 8 + lrow8) * TSEQ + ktLo * 64 + lchunk * 8, &Vs[0][c * 512]);
        }
        __syncthreads();

        int cur = 0;
        for (int kt = ktLo; kt < ktHi; ++kt) {
            if (kt + 1 < ktHi) {
                int nb = cur ^ 1;
#pragma unroll
                for (int i2 = 0; i2 < 2; ++i2) {
                    int c = w * 2 + i2;
                    GLD16(Kg + (size_t)((kt + 1) * 64 + c * 8 + lrow8) * HD + lchunk * 8,
                          &Ks[nb][c * 512]);
                    GLD16(Vg + (size_t)(c * 8 + lrow8) * TSEQ + (kt + 1) * 64 + lchunk * 8,
                          &Vs[nb][c * 512]);
                }
            }
            const u16* Kc = Ks[cur];
            const u16* Vc = Vs[cur];

            // S^T: s[f][qn][r] = S[q][k=kt*64+f*16+g*4+r]; K-frag shared by both qn
            f32x4 s[4][2] = {};
#pragma unroll
            for (int f = 0; f < 4; ++f)
#pragma unroll
                for (int ks = 0; ks < 2; ++ks) {
                    bf16x8 bk = *reinterpret_cast<const bf16x8*>(
                        Kc + (f * 16 + l15) * 64 + (((ks * 4 + g) ^ (l15 & 7)) * 8));
                    s[f][0] = __builtin_amdgcn_mfma_f32_16x16x32_bf16(bk, qa[0][ks], s[f][0], 0, 0, 0);
                    s[f][1] = __builtin_amdgcn_mfma_f32_16x16x32_bf16(bk, qa[1][ks], s[f][1], 0, 0, 0);
                }

            // causal mask on tiles crossing the diagonal band (kt >= 2t)
            if (kt >= 2 * t) {
#pragma unroll
                for (int f = 0; f < 4; ++f)
#pragma unroll
                    for (int r = 0; r < 4; ++r) {
                        int kg = (kt << 6) + f * 16 + g * 4 + r;
                        if (kg > qrow0) s[f][0][r] = -1e30f;
                        if (kg > qrow1) s[f][1][r] = -1e30f;
                    }
            }

            // per-qn lane-local online softmax + bf16 pack
            u32 pk0[2][4], pk1[2][4];
#pragma unroll
            for (int qn = 0; qn < 2; ++qn) {
                float rmax = -1e30f;
#pragma unroll
                for (int f = 0; f < 4; ++f)
                    rmax = fmaxf(rmax, fmaxf(fmaxf(s[f][qn][0], s[f][qn][1]),
                                             fmaxf(s[f][qn][2], s[f][qn][3])));
                rmax = fmaxf(rmax, __shfl_xor(rmax, 16));
                rmax = fmaxf(rmax, __shfl_xor(rmax, 32));

                if (__any(rmax - m[qn] > THRU)) {
                    float mnew = fmaxf(m[qn], rmax);
                    float alpha = exp2f((m[qn] - mnew) * SC);
                    m[qn] = mnew;
#pragma unroll
                    for (int r = 0; r < 4; ++r)
                        os[qn][r] *= alpha;
#pragma unroll
                    for (int nf = 0; nf < 4; ++nf)
#pragma unroll
                        for (int r = 0; r < 4; ++r)
                            o[qn][nf][r] *= alpha;
                }
                const float mc = m[qn] * SC;
#pragma unroll
                for (int f = 0; f < 4; ++f) {
                    float p0 = exp2f(__builtin_fmaf(s[f][qn][0], SC, -mc));
                    float p1 = exp2f(__builtin_fmaf(s[f][qn][1], SC, -mc));
                    float p2 = exp2f(__builtin_fmaf(s[f][qn][2], SC, -mc));
                    float p3 = exp2f(__builtin_fmaf(s[f][qn][3], SC, -mc));
                    pk0[qn][f] = cvt_pk_bf16(p0, p1);
                    pk1[qn][f] = cvt_pk_bf16(p2, p3);
                }
            }

            // O^T += mfma(V^T-frag, P-frag); V-frag shared by both qn
#pragma unroll
            for (int ks = 0; ks < 2; ++ks) {
                bf16x8 pb[2];
#pragma unroll
                for (int qn = 0; qn < 2; ++qn) {
                    u32 t00 = (u32)__shfl((int)pk0[qn][2 * ks], srcA);
                    u32 t01 = (u32)__shfl((int)pk0[qn][2 * ks + 1], srcA);
                    u32 t10 = (u32)__shfl((int)pk1[qn][2 * ks], srcA);
                    u32 t11 = (u32)__shfl((int)pk1[qn][2 * ks + 1], srcA);
                    u32 t20 = (u32)__shfl((int)pk0[qn][2 * ks], srcB);
                    u32 t21 = (u32)__shfl((int)pk0[qn][2 * ks + 1], srcB);
                    u32 t30 = (u32)__shfl((int)pk1[qn][2 * ks], srcB);
                    u32 t31 = (u32)__shfl((int)pk1[qn][2 * ks + 1], srcB);
                    u32x4 bb;
                    bb.x = losel ? t00 : t01;
                    bb.y = losel ? t10 : t11;
                    bb.z = losel ? t20 : t21;
                    bb.w = losel ? t30 : t31;
                    pb[qn] = __builtin_bit_cast(bf16x8, bb);
                }
                os[0] = __builtin_amdgcn_mfma_f32_16x16x32_bf16(onesA, pb[0], os[0], 0, 0, 0);
                os[1] = __builtin_amdgcn_mfma_f32_16x16x32_bf16(onesA, pb[1], os[1], 0, 0, 0);
#pragma unroll
                for (int nf = 0; nf < 4; ++nf) {
                    bf16x8 bv = *reinterpret_cast<const bf16x8*>(
                        Vc + (nf * 16 + l15) * 64 + (((ks * 4 + g) ^ (l15 & 7)) * 8));
                    o[0][nf] = __builtin_amdgcn_mfma_f32_16x16x32_bf16(bv, pb[0], o[0][nf], 0, 0, 0);
                    o[1][nf] = __builtin_amdgcn_mfma_f32_16x16x32_bf16(bv, pb[1], o[1][nf], 0, 0, 0);
                }
            }
            __syncthreads();
            cur ^= 1;
        }
    }

    // partial epilogue: UNNORMALIZED o (bf16) + m, l (f32)
    const size_t oSplit = (size_t)32 * TSEQ * HD;
    const size_t mlSplit = (size_t)32 * 2 * TSEQ;
#pragma unroll
    for (int qn = 0; qn < 2; ++qn) {
        int qrow = qn ? qrow1 : qrow0;
        u16* oRow = oPart + split * oSplit + ((size_t)bh * TSEQ + qrow) * HD;
#pragma unroll
        for (int nf = 0; nf < 4; ++nf) {
            int d0 = nf * 16 + g * 4;
            u32 p01 = cvt_pk_bf16(o[qn][nf][0], o[qn][nf][1]);
            u32 p23 = cvt_pk_bf16(o[qn][nf][2], o[qn][nf][3]);
            *reinterpret_cast<u32*>(oRow + d0) = p01;
            *reinterpret_cast<u32*>(oRow + d0 + 2) = p23;
        }
        if (g == 0) {
            float* mlH = mlPart + split * mlSplit;
            mlH[((size_t)bh * 2 + 0) * TSEQ + qrow] = m[qn];
            mlH[((size_t)bh * 2 + 1) * TSEQ + qrow] = os[qn][0];
        }
    }
}

// ---------- merge NS K-split partials -> attn [B*T][NE] bf16 ----------
template <int NS>
__global__ void k_merge(const u16* __restrict__ oPart, const float* __restrict__ mlPart,
                        u16* __restrict__ attn_out) {
    const float SC = 0.125f * 1.44269504f;
    int tid = blockIdx.x * blockDim.x + threadIdx.x;  // 32*2048*8
    int dblk = tid & 7;
    int q = (tid >> 3) & 2047;
    int bh = tid >> 14;
    const size_t oSplit = (size_t)32 * TSEQ * HD;
    const size_t mlSplit = (size_t)32 * 2 * TSEQ;
    float mw[NS], lw[NS];
    float M = -3e38f;
#pragma unroll
    for (int s = 0; s < NS; ++s) {
        mw[s] = mlPart[s * mlSplit + ((size_t)bh * 2 + 0) * TSEQ + q];
        lw[s] = mlPart[s * mlSplit + ((size_t)bh * 2 + 1) * TSEQ + q];
        M = fmaxf(M, mw[s]);
    }
    float L = 0.f, fs[NS];
#pragma unroll
    for (int s = 0; s < NS; ++s) {
        fs[s] = exp2f((mw[s] - M) * SC);
        L += lw[s] * fs[s];
    }
    float inv = 1.0f / L;
    float acc[8] = {};
#pragma unroll
    for (int s = 0; s < NS; ++s) {
        float wgt = fs[s] * inv;
        const u32* p = (const u32*)(oPart + s * oSplit + ((size_t)bh * TSEQ + q) * HD + dblk * 8);
#pragma unroll
        for (int i = 0; i < 4; ++i) {
            u32 v = p[i];
            acc[2 * i] += bf2f(v & 0xffffu) * wgt;
            acc[2 * i + 1] += bf2f(v >> 16) * wgt;
        }
    }
    u32 outw[4];
#pragma unroll
    for (int i = 0; i < 4; ++i)
        outw[i] = cvt_pk_bf16(acc[2 * i], acc[2 * i + 1]);
    int bb = bh >> 4, h = bh & 15;
    u16* dst = attn_out + ((size_t)(bb * TSEQ + q) * NE) + h * HD + dblk * 8;
    *reinterpret_cast<u32x4*>(dst) = *reinterpret_cast<const u32x4*>(outw);
}

extern "C" void kernel_launch(void* const* d_in, const int* in_sizes, int n_in,
                              void* d_out, int out_size, void* d_ws, size_t ws_size,
                              hipStream_t stream) {
    const float* x = (const float*)d_in[0];
    const float* W_attn = (const float*)d_in[1];
    const float* b_attn = (const float*)d_in[2];
    const float* W_proj = (const float*)d_in[3];
    const float* b_proj = (const float*)d_in[4];
    float* out = (float*)d_out;

    char* ws = (char*)d_ws;
    const int M = BATCH * TSEQ;  // 4096
    const size_t headsz = (size_t)BATCH * NH * TSEQ * HD;  // 4M elems
    const int mergeGrid = (32 * TSEQ * 8) / 256;
    const int prepGrid = 2048 + 3072 + 1024;
    const bool big = ws_size >= (size_t)74 * MB;

    if (big) {
        // layout (74MB): xb 0..8 | WaT 8..14 | WpT 14..16 | qkvb 16..40 |
        //                oPart[4] 40..72 | mlPart 72..74 | attn overwrites q 16..24
        u16* xb    = (u16*)(ws);
        u16* WaT   = (u16*)(ws + 8 * MB);
        u16* WpT   = (u16*)(ws + 14 * MB);
        u16* qkvb  = (u16*)(ws + 16 * MB);
        u16* oPart = (u16*)(ws + 40 * MB);
        float* mlP = (float*)(ws + 72 * MB);
        u16* attn  = (u16*)(ws + 16 * MB);

        k_prep<<<dim3(prepGrid), 256, 0, stream>>>(x, xb, W_attn, W_proj, WaT, WpT);
        k_gemm_bt<0, 128><<<dim3(M / 128, (3 * NE) / 128), 256, 0, stream>>>(xb, WaT, b_attn, qkvb, M, 3 * NE, NE);
        k_attn<4><<<dim3(16 * 4 * 32), 256, 0, stream>>>(qkvb, qkvb + headsz, qkvb + 2 * headsz, oPart, mlP);
        k_merge<4><<<dim3(mergeGrid), 256, 0, stream>>>(oPart, mlP, attn);
        k_gemm_bt<1, 64><<<dim3(M / 64, NE / 128), 256, 0, stream>>>(attn, WpT, b_proj, out, M, NE, NE);
    } else {
        // fallback layout (43MB peak), NS=2
        u16* xb    = (u16*)(ws);
        u16* WaT   = (u16*)(ws + 8 * MB);
        u16* qkvb  = (u16*)(ws + 16 * MB);
        u16* WpT   = (u16*)(ws + 40 * MB);
        float* mlP = (float*)(ws + 42 * MB);
        u16* oPart = (u16*)(ws);             // halves at 0..8 and 8..16
        u16* attn  = (u16*)(ws + 16 * MB);   // overwrites dead q

        k_prep<<<dim3(prepGrid), 256, 0, stream>>>(x, xb, W_attn, W_proj, WaT, WpT);
        k_gemm_bt<0, 128><<<dim3(M / 128, (3 * NE) / 128), 256, 0, stream>>>(xb, WaT, b_attn, qkvb, M, 3 * NE, NE);
        k_attn<2><<<dim3(16 * 2 * 32), 256, 0, stream>>>(qkvb, qkvb + headsz, qkvb + 2 * headsz, oPart, mlP);
        k_merge<2><<<dim3(mergeGrid), 256, 0, stream>>>(oPart, mlP, attn);
        k_gemm_bt<1, 64><<<dim3(M / 64, NE / 128), 256, 0, stream>>>(attn, WpT, b_proj, out, M, NE, NE);
    }
}

// Round 24
// 117.195 us; speedup vs baseline: 1.0022x; 1.0022x over previous
//
#include <hip/hip_runtime.h>
#include <hip/hip_bf16.h>

#define NE 1024       // N_EMBD
#define NH 16         // N_HEAD
#define HD 64         // HEAD_SIZE
#define TSEQ 2048
#define BATCH 2
#define MB (1024u * 1024u)

typedef __attribute__((ext_vector_type(8))) short bf16x8;
typedef __attribute__((ext_vector_type(4))) float f32x4;
typedef __attribute__((ext_vector_type(4))) unsigned int u32x4;
typedef unsigned short u16;
typedef unsigned int u32;

__device__ inline u16 f2bf(float f) {
    __hip_bfloat16 h = __float2bfloat16(f);
    return *reinterpret_cast<u16*>(&h);
}

__device__ inline float bf2f(u32 bits) {
    u32 v = bits << 16;
    return __builtin_bit_cast(float, v);
}

__device__ inline u32 cvt_pk_bf16(float lo, float hi) {
    u32 r;
    asm("v_cvt_pk_bf16_f32 %0, %1, %2" : "=v"(r) : "v"(lo), "v"(hi));
    return r;
}

#define GLD16(gptr, lptr)                                                        \
    __builtin_amdgcn_global_load_lds(                                            \
        (const __attribute__((address_space(1))) void*)(gptr),                   \
        (__attribute__((address_space(3))) void*)(lptr), 16, 0, 0)

// ---------- fused prep: x f32->bf16 convert + both weight transposes ----------
__global__ void k_prep(const float* __restrict__ x, u16* __restrict__ xb,
                       const float* __restrict__ Wa, const float* __restrict__ Wp,
                       u16* __restrict__ WaT, u16* __restrict__ WpT) {
    __shared__ float tile[32][33];
    const int bidx = blockIdx.x;
    if (bidx < 2048) {
        const int n4 = (BATCH * TSEQ * NE) / 4;
        int i = bidx * 256 + threadIdx.x;
        int stride = 2048 * 256;
        for (; i < n4; i += stride) {
            float4 v = reinterpret_cast<const float4*>(x)[i];
            ushort4 o;
            o.x = f2bf(v.x); o.y = f2bf(v.y); o.z = f2bf(v.z); o.w = f2bf(v.w);
            reinterpret_cast<ushort4*>(xb)[i] = o;
        }
        return;
    }
    int tb = bidx - 2048;
    const bool isA = tb < 3072;
    if (!isA) tb -= 3072;
    const float* in = isA ? Wa : Wp;
    u16* out = isA ? WaT : WpT;
    const int N = isA ? 3 * NE : NE;
    const int nbn = N / 32;
    int bn = (tb % nbn) * 32;
    int bk = (tb / nbn) * 32;
    int tx = threadIdx.x & 31, ty = threadIdx.x >> 5;
#pragma unroll
    for (int i = 0; i < 32; i += 8)
        tile[ty + i][tx] = in[(size_t)(bk + ty + i) * N + bn + tx];
    __syncthreads();
#pragma unroll
    for (int i = 0; i < 32; i += 8)
        out[(size_t)(bn + ty + i) * NE + bk + tx] = f2bf(tile[tx][ty + i]);
}

// ---------- GEMM: C[M,N] = A[M,K] * Bt[N,K]^T + bias ----------
// BK=32, double-buffered, BM templated, __launch_bounds__(256,3) (R20 best).
// MODE 0 (BM=128): q/k scatter [B,H,T,D]; v via LDS transpose -> [B,H,D,T].
// MODE 1: plain f32 out.
template <int MODE, int BM>
__global__ __launch_bounds__(256, 3) void k_gemm_bt(
    const u16* __restrict__ A, const u16* __restrict__ Bt,
    const float* __restrict__ bias, void* __restrict__ outp,
    int M, int N, int K) {
    constexpr int MI = BM / 32;
    constexpr int ACALLS = BM / 64;
    __shared__ __align__(16) u16 As[2][BM * 32];
    __shared__ __align__(16) u16 Bs[2][128 * 32];
    const int l = threadIdx.x & 63;
    const int w = threadIdx.x >> 6;
    const int m0 = blockIdx.x * BM;
    const int n0 = blockIdx.y * 128;
    const int wr = w >> 1, wc = w & 1;
    const int l15 = l & 15, g = l >> 4;
    const int srow = l >> 2;
    const int scol = (l & 3) * 8;

    f32x4 acc[MI][4] = {};
    const int nkt = K >> 5;

#pragma unroll
    for (int i = 0; i < ACALLS; ++i) {
        int c = w * ACALLS + i;
        GLD16(A + (size_t)(m0 + c * 16 + srow) * K + scol, &As[0][c * 512]);
    }
#pragma unroll
    for (int i = 0; i < 2; ++i) {
        int c = w * 2 + i;
        GLD16(Bt + (size_t)(n0 + c * 16 + srow) * K + scol, &Bs[0][c * 512]);
    }
    __syncthreads();

    int cur = 0;
    for (int kt = 0; kt < nkt; ++kt) {
        if (kt + 1 < nkt) {
            int nb = cur ^ 1;
            int kc = ((kt + 1) << 5) + scol;
#pragma unroll
            for (int i = 0; i < ACALLS; ++i) {
                int c = w * ACALLS + i;
                GLD16(A + (size_t)(m0 + c * 16 + srow) * K + kc, &As[nb][c * 512]);
            }
#pragma unroll
            for (int i = 0; i < 2; ++i) {
                int c = w * 2 + i;
                GLD16(Bt + (size_t)(n0 + c * 16 + srow) * K + kc, &Bs[nb][c * 512]);
            }
        }
        bf16x8 af[MI], bfr[4];
#pragma unroll
        for (int mi = 0; mi < MI; ++mi)
            af[mi] = *reinterpret_cast<const bf16x8*>(
                &As[cur][(wr * (BM / 2) + mi * 16 + l15) * 32 + g * 8]);
#pragma unroll
        for (int ni = 0; ni < 4; ++ni)
            bfr[ni] = *reinterpret_cast<const bf16x8*>(
                &Bs[cur][(wc * 64 + ni * 16 + l15) * 32 + g * 8]);
#pragma unroll
        for (int mi = 0; mi < MI; ++mi)
#pragma unroll
            for (int ni = 0; ni < 4; ++ni)
                acc[mi][ni] = __builtin_amdgcn_mfma_f32_16x16x32_bf16(af[mi], bfr[ni], acc[mi][ni], 0, 0, 0);
        __syncthreads();
        cur ^= 1;
    }

    if (MODE == 1) {
        float* C = (float*)outp;
#pragma unroll
        for (int mi = 0; mi < MI; ++mi)
#pragma unroll
            for (int ni = 0; ni < 4; ++ni) {
                int n = n0 + wc * 64 + ni * 16 + l15;
                float bv = bias[n];
#pragma unroll
                for (int r = 0; r < 4; ++r) {
                    int m = m0 + wr * (BM / 2) + mi * 16 + g * 4 + r;
                    C[(size_t)m * N + n] = acc[mi][ni][r] + bv;
                }
            }
    } else {
        u16* qkv = (u16*)outp;
        const size_t headsz = (size_t)BATCH * NH * TSEQ * HD;
        const int whichB = n0 >> 10;
        if (whichB < 2) {
#pragma unroll
            for (int mi = 0; mi < MI; ++mi)
#pragma unroll
                for (int ni = 0; ni < 4; ++ni) {
                    int n = n0 + wc * 64 + ni * 16 + l15;
                    float bv = bias[n];
                    int c = n & 1023;
                    int h = c >> 6, d = c & 63;
#pragma unroll
                    for (int r = 0; r < 4; ++r) {
                        int m = m0 + wr * (BM / 2) + mi * 16 + g * 4 + r;
                        int b = m >> 11, t = m & 2047;
                        float v = acc[mi][ni][r] + bv;
                        size_t dst = (size_t)whichB * headsz +
                                     ((size_t)(b * NH + h) * TSEQ + t) * HD + d;
                        qkv[dst] = f2bf(v);
                    }
                }
        } else {
            // v: transpose 128x128 subtile through dead staging LDS -> coalesced [B,H,D,T]
            u16* Vt = &As[0][0];
            __syncthreads();
#pragma unroll
            for (int mi = 0; mi < MI; ++mi)
#pragma unroll
                for (int ni = 0; ni < 4; ++ni) {
                    int nl = wc * 64 + ni * 16 + l15;
                    int ml = wr * (BM / 2) + mi * 16 + g * 4;
                    float bv = bias[n0 + nl];
                    u32* p = reinterpret_cast<u32*>(&Vt[nl * 128 + ml]);
                    p[0] = cvt_pk_bf16(acc[mi][ni][0] + bv, acc[mi][ni][1] + bv);
                    p[1] = cvt_pk_bf16(acc[mi][ni][2] + bv, acc[mi][ni][3] + bv);
                }
            __syncthreads();
            int nl = threadIdx.x >> 1;
            int mh = (threadIdx.x & 1) * 64;
            int b = m0 >> 11, t0l = m0 & 2047;
            int h = ((n0 & 1023) >> 6) + (nl >> 6);
            int d = nl & 63;
            u16* dst = qkv + 2 * headsz + ((size_t)(b * NH + h) * HD + d) * TSEQ + t0l + mh;
#pragma unroll
            for (int j = 0; j < 8; ++j)
                *reinterpret_cast<u32x4*>(dst + j * 8) =
                    *reinterpret_cast<const u32x4*>(&Vt[nl * 128 + mh + j * 8]);
        }
    }
}

// ---------- causal flash attention: QBLK=128 (2 q-frags/wave), NS-way K-split ----------
// grid: 16 * NS * 32 blocks, 4 waves, 32KB LDS, heavy-first. NS=4 measured optimum
// (NS=2: 49.5+5.0; NS=3: 48.2+5.4; NS=4: 46.4+6.7 us). setprio KEPT: removing it
// regressed +1us (R23) — cross-block arbitration pays with 4 resident blocks.
// launch_bounds (256,4): (256,5) spilled (R14); single-buffer V regressed (R17).
template <int NS>
__global__ __launch_bounds__(256, 4) void k_attn(
    const u16* __restrict__ qb, const u16* __restrict__ kb, const u16* __restrict__ vtb,
    u16* __restrict__ oPart, float* __restrict__ mlPart) {
    __shared__ __align__(16) u16 Ks[2][64 * 64];
    __shared__ __align__(16) u16 Vs[2][64 * 64];
    const int l = threadIdx.x & 63;
    const int w = threadIdx.x >> 6;
    const int g = l >> 4, l15 = l & 15;

    const int bid = blockIdx.x;
    const int t = 15 - (bid / (NS * 32));   // 128-row q-tile, heavy first
    const int split = (bid / 32) % NS;
    const int bh = bid & 31;
    const int q0 = t * 128;
    const int ntk = 2 * t + 2;
    const int ktLo = (split * ntk) / NS;
    const int ktHi = ((split + 1) * ntk) / NS;

    const size_t base = (size_t)bh * TSEQ * HD;
    const u16* Q = qb + base;
    const u16* Kg = kb + base;
    const u16* Vg = vtb + base;  // [64 d][2048 t]

    const int lrow8 = l >> 3;
    const int lchunk = (l & 7) ^ lrow8;  // inverse-swizzled source chunk

    const int qrow0 = q0 + w * 32 + l15;
    const int qrow1 = qrow0 + 16;
    bf16x8 qa[2][2];  // [qn][ks]
#pragma unroll
    for (int ks = 0; ks < 2; ++ks) {
        qa[0][ks] = *reinterpret_cast<const bf16x8*>(Q + (size_t)qrow0 * HD + ks * 32 + g * 8);
        qa[1][ks] = *reinterpret_cast<const bf16x8*>(Q + (size_t)qrow1 * HD + ks * 32 + g * 8);
    }

    float m[2] = {0.f, 0.f};       // SAFE init (fully-masked rows stay finite)
    f32x4 o[2][4] = {};            // [qn][nf]
    f32x4 os[2] = {};              // ones-MFMA row-sum accumulators

    const float SC = 0.125f * 1.44269504f;  // log2(e)/sqrt(64)
    const float THRU = 44.3614f;            // 8/SC

    const int srcA = ((2 * g) & 3) * 16 + l15;
    const int srcB = ((2 * g + 1) & 3) * 16 + l15;
    const bool losel = (g < 2);

    u32x4 onesw = {0x3F803F80u, 0x3F803F80u, 0x3F803F80u, 0x3F803F80u};
    const bf16x8 onesA = __builtin_bit_cast(bf16x8, onesw);

    if (ktLo < ktHi) {
#pragma unroll
        for (int i2 = 0; i2 < 2; ++i2) {
            int c = w * 2 + i2;
            GLD16(Kg + (size_t)(ktLo * 64 + c * 8 + lrow8) * HD + lchunk * 8, &Ks[0][c * 512]);
            GLD16(Vg + (size_t)(c * 8 + lrow8) * TSEQ + ktLo * 64 + lchunk * 8, &Vs[0][c * 512]);
        }
        __syncthreads();

        int cur = 0;
        for (int kt = ktLo; kt < ktHi; ++kt) {
            if (kt + 1 < ktHi) {
                int nb = cur ^ 1;
#pragma unroll
                for (int i2 = 0; i2 < 2; ++i2) {
                    int c = w * 2 + i2;
                    GLD16(Kg + (size_t)((kt + 1) * 64 + c * 8 + lrow8) * HD + lchunk * 8,
                          &Ks[nb][c * 512]);
                    GLD16(Vg + (size_t)(c * 8 + lrow8) * TSEQ + (kt + 1) * 64 + lchunk * 8,
                          &Vs[nb][c * 512]);
                }
            }
            const u16* Kc = Ks[cur];
            const u16* Vc = Vs[cur];

            // S^T: s[f][qn][r] = S[q][k=kt*64+f*16+g*4+r]; K-frag shared by both qn
            f32x4 s[4][2] = {};
            __builtin_amdgcn_s_setprio(1);
#pragma unroll
            for (int f = 0; f < 4; ++f)
#pragma unroll
                for (int ks = 0; ks < 2; ++ks) {
                    bf16x8 bk = *reinterpret_cast<const bf16x8*>(
                        Kc + (f * 16 + l15) * 64 + (((ks * 4 + g) ^ (l15 & 7)) * 8));
                    s[f][0] = __builtin_amdgcn_mfma_f32_16x16x32_bf16(bk, qa[0][ks], s[f][0], 0, 0, 0);
                    s[f][1] = __builtin_amdgcn_mfma_f32_16x16x32_bf16(bk, qa[1][ks], s[f][1], 0, 0, 0);
                }
            __builtin_amdgcn_s_setprio(0);

            // causal mask on tiles crossing the diagonal band (kt >= 2t)
            if (kt >= 2 * t) {
#pragma unroll
                for (int f = 0; f < 4; ++f)
#pragma unroll
                    for (int r = 0; r < 4; ++r) {
                        int kg = (kt << 6) + f * 16 + g * 4 + r;
                        if (kg > qrow0) s[f][0][r] = -1e30f;
                        if (kg > qrow1) s[f][1][r] = -1e30f;
                    }
            }

            // per-qn lane-local online softmax + bf16 pack
            u32 pk0[2][4], pk1[2][4];
#pragma unroll
            for (int qn = 0; qn < 2; ++qn) {
                float rmax = -1e30f;
#pragma unroll
                for (int f = 0; f < 4; ++f)
                    rmax = fmaxf(rmax, fmaxf(fmaxf(s[f][qn][0], s[f][qn][1]),
                                             fmaxf(s[f][qn][2], s[f][qn][3])));
                rmax = fmaxf(rmax, __shfl_xor(rmax, 16));
                rmax = fmaxf(rmax, __shfl_xor(rmax, 32));

                if (__any(rmax - m[qn] > THRU)) {
                    float mnew = fmaxf(m[qn], rmax);
                    float alpha = exp2f((m[qn] - mnew) * SC);
                    m[qn] = mnew;
#pragma unroll
                    for (int r = 0; r < 4; ++r)
                        os[qn][r] *= alpha;
#pragma unroll
                    for (int nf = 0; nf < 4; ++nf)
#pragma unroll
                        for (int r = 0; r < 4; ++r)
                            o[qn][nf][r] *= alpha;
                }
                const float mc = m[qn] * SC;
#pragma unroll
                for (int f = 0; f < 4; ++f) {
                    float p0 = exp2f(__builtin_fmaf(s[f][qn][0], SC, -mc));
                    float p1 = exp2f(__builtin_fmaf(s[f][qn][1], SC, -mc));
                    float p2 = exp2f(__builtin_fmaf(s[f][qn][2], SC, -mc));
                    float p3 = exp2f(__builtin_fmaf(s[f][qn][3], SC, -mc));
                    pk0[qn][f] = cvt_pk_bf16(p0, p1);
                    pk1[qn][f] = cvt_pk_bf16(p2, p3);
                }
            }

            // O^T += mfma(V^T-frag, P-frag); V-frag shared by both qn
            __builtin_amdgcn_s_setprio(1);
#pragma unroll
            for (int ks = 0; ks < 2; ++ks) {
                bf16x8 pb[2];
#pragma unroll
                for (int qn = 0; qn < 2; ++qn) {
                    u32 t00 = (u32)__shfl((int)pk0[qn][2 * ks], srcA);
                    u32 t01 = (u32)__shfl((int)pk0[qn][2 * ks + 1], srcA);
                    u32 t10 = (u32)__shfl((int)pk1[qn][2 * ks], srcA);
                    u32 t11 = (u32)__shfl((int)pk1[qn][2 * ks + 1], srcA);
                    u32 t20 = (u32)__shfl((int)pk0[qn][2 * ks], srcB);
                    u32 t21 = (u32)__shfl((int)pk0[qn][2 * ks + 1], srcB);
                    u32 t30 = (u32)__shfl((int)pk1[qn][2 * ks], srcB);
                    u32 t31 = (u32)__shfl((int)pk1[qn][2 * ks + 1], srcB);
                    u32x4 bb;
                    bb.x = losel ? t00 : t01;
                    bb.y = losel ? t10 : t11;
                    bb.z = losel ? t20 : t21;
                    bb.w = losel ? t30 : t31;
                    pb[qn] = __builtin_bit_cast(bf16x8, bb);
                }
                os[0] = __builtin_amdgcn_mfma_f32_16x16x32_bf16(onesA, pb[0], os[0], 0, 0, 0);
                os[1] = __builtin_amdgcn_mfma_f32_16x16x32_bf16(onesA, pb[1], os[1], 0, 0, 0);
#pragma unroll
                for (int nf = 0; nf < 4; ++nf) {
                    bf16x8 bv = *reinterpret_cast<const bf16x8*>(
                        Vc + (nf * 16 + l15) * 64 + (((ks * 4 + g) ^ (l15 & 7)) * 8));
                    o[0][nf] = __builtin_amdgcn_mfma_f32_16x16x32_bf16(bv, pb[0], o[0][nf], 0, 0, 0);
                    o[1][nf] = __builtin_amdgcn_mfma_f32_16x16x32_bf16(bv, pb[1], o[1][nf], 0, 0, 0);
                }
            }
            __builtin_amdgcn_s_setprio(0);
            __syncthreads();
            cur ^= 1;
        }
    }

    // partial epilogue: UNNORMALIZED o (bf16) + m, l (f32)
    const size_t oSplit = (size_t)32 * TSEQ * HD;
    const size_t mlSplit = (size_t)32 * 2 * TSEQ;
#pragma unroll
    for (int qn = 0; qn < 2; ++qn) {
        int qrow = qn ? qrow1 : qrow0;
        u16* oRow = oPart + split * oSplit + ((size_t)bh * TSEQ + qrow) * HD;
#pragma unroll
        for (int nf = 0; nf < 4; ++nf) {
            int d0 = nf * 16 + g * 4;
            u32 p01 = cvt_pk_bf16(o[qn][nf][0], o[qn][nf][1]);
            u32 p23 = cvt_pk_bf16(o[qn][nf][2], o[qn][nf][3]);
            *reinterpret_cast<u32*>(oRow + d0) = p01;
            *reinterpret_cast<u32*>(oRow + d0 + 2) = p23;
        }
        if (g == 0) {
            float* mlH = mlPart + split * mlSplit;
            mlH[((size_t)bh * 2 + 0) * TSEQ + qrow] = m[qn];
            mlH[((size_t)bh * 2 + 1) * TSEQ + qrow] = os[qn][0];
        }
    }
}

// ---------- merge NS K-split partials -> attn [B*T][NE] bf16 ----------
template <int NS>
__global__ void k_merge(const u16* __restrict__ oPart, const float* __restrict__ mlPart,
                        u16* __restrict__ attn_out) {
    const float SC = 0.125f * 1.44269504f;
    int tid = blockIdx.x * blockDim.x + threadIdx.x;  // 32*2048*8
    int dblk = tid & 7;
    int q = (tid >> 3) & 2047;
    int bh = tid >> 14;
    const size_t oSplit = (size_t)32 * TSEQ * HD;
    const size_t mlSplit = (size_t)32 * 2 * TSEQ;
    float mw[NS], lw[NS];
    float M = -3e38f;
#pragma unroll
    for (int s = 0; s < NS; ++s) {
        mw[s] = mlPart[s * mlSplit + ((size_t)bh * 2 + 0) * TSEQ + q];
        lw[s] = mlPart[s * mlSplit + ((size_t)bh * 2 + 1) * TSEQ + q];
        M = fmaxf(M, mw[s]);
    }
    float L = 0.f, fs[NS];
#pragma unroll
    for (int s = 0; s < NS; ++s) {
        fs[s] = exp2f((mw[s] - M) * SC);
        L += lw[s] * fs[s];
    }
    float inv = 1.0f / L;
    float acc[8] = {};
#pragma unroll
    for (int s = 0; s < NS; ++s) {
        float wgt = fs[s] * inv;
        const u32* p = (const u32*)(oPart + s * oSplit + ((size_t)bh * TSEQ + q) * HD + dblk * 8);
#pragma unroll
        for (int i = 0; i < 4; ++i) {
            u32 v = p[i];
            acc[2 * i] += bf2f(v & 0xffffu) * wgt;
            acc[2 * i + 1] += bf2f(v >> 16) * wgt;
        }
    }
    u32 outw[4];
#pragma unroll
    for (int i = 0; i < 4; ++i)
        outw[i] = cvt_pk_bf16(acc[2 * i], acc[2 * i + 1]);
    int bb = bh >> 4, h = bh & 15;
    u16* dst = attn_out + ((size_t)(bb * TSEQ + q) * NE) + h * HD + dblk * 8;
    *reinterpret_cast<u32x4*>(dst) = *reinterpret_cast<const u32x4*>(outw);
}

extern "C" void kernel_launch(void* const* d_in, const int* in_sizes, int n_in,
                              void* d_out, int out_size, void* d_ws, size_t ws_size,
                              hipStream_t stream) {
    const float* x = (const float*)d_in[0];
    const float* W_attn = (const float*)d_in[1];
    const float* b_attn = (const float*)d_in[2];
    const float* W_proj = (const float*)d_in[3];
    const float* b_proj = (const float*)d_in[4];
    float* out = (float*)d_out;

    char* ws = (char*)d_ws;
    const int M = BATCH * TSEQ;  // 4096
    const size_t headsz = (size_t)BATCH * NH * TSEQ * HD;  // 4M elems
    const int mergeGrid = (32 * TSEQ * 8) / 256;
    const int prepGrid = 2048 + 3072 + 1024;
    const bool big = ws_size >= (size_t)74 * MB;

    if (big) {
        // layout (74MB): xb 0..8 | WaT 8..14 | WpT 14..16 | qkvb 16..40 |
        //                oPart[4] 40..72 | mlPart 72..74 | attn overwrites q 16..24
        u16* xb    = (u16*)(ws);
        u16* WaT   = (u16*)(ws + 8 * MB);
        u16* WpT   = (u16*)(ws + 14 * MB);
        u16* qkvb  = (u16*)(ws + 16 * MB);
        u16* oPart = (u16*)(ws + 40 * MB);
        float* mlP = (float*)(ws + 72 * MB);
        u16* attn  = (u16*)(ws + 16 * MB);

        k_prep<<<dim3(prepGrid), 256, 0, stream>>>(x, xb, W_attn, W_proj, WaT, WpT);
        k_gemm_bt<0, 128><<<dim3(M / 128, (3 * NE) / 128), 256, 0, stream>>>(xb, WaT, b_attn, qkvb, M, 3 * NE, NE);
        k_attn<4><<<dim3(16 * 4 * 32), 256, 0, stream>>>(qkvb, qkvb + headsz, qkvb + 2 * headsz, oPart, mlP);
        k_merge<4><<<dim3(mergeGrid), 256, 0, stream>>>(oPart, mlP, attn);
        k_gemm_bt<1, 64><<<dim3(M / 64, NE / 128), 256, 0, stream>>>(attn, WpT, b_proj, out, M, NE, NE);
    } else {
        // fallback layout (43MB peak), NS=2
        u16* xb    = (u16*)(ws);
        u16* WaT   = (u16*)(ws + 8 * MB);
        u16* qkvb  = (u16*)(ws + 16 * MB);
        u16* WpT   = (u16*)(ws + 40 * MB);
        float* mlP = (float*)(ws + 42 * MB);
        u16* oPart = (u16*)(ws);             // halves at 0..8 and 8..16
        u16* attn  = (u16*)(ws + 16 * MB);   // overwrites dead q

        k_prep<<<dim3(prepGrid), 256, 0, stream>>>(x, xb, W_attn, W_proj, WaT, WpT);
        k_gemm_bt<0, 128><<<dim3(M / 128, (3 * NE) / 128), 256, 0, stream>>>(xb, WaT, b_attn, qkvb, M, 3 * NE, NE);
        k_attn<2><<<dim3(16 * 2 * 32), 256, 0, stream>>>(qkvb, qkvb + headsz, qkvb + 2 * headsz, oPart, mlP);
        k_merge<2><<<dim3(mergeGrid), 256, 0, stream>>>(oPart, mlP, attn);
        k_gemm_bt<1, 64><<<dim3(M / 64, NE / 128), 256, 0, stream>>>(attn, WpT, b_proj, out, M, NE, NE);
    }
}